// Round 6
// baseline (197.457 us; speedup 1.0000x reference)
//
#include <hip/hip_runtime.h>
#include <math.h>

// Variance-gamma MC option pricer — R5: two-path interleaved chains per wave.
// R4 was latency-bound (VALUBusy 49%): one serial scan/readlane/exp chain per
// wave. R5 interleaves TWO independent paths inside process2 (alternating DPP
// scan steps), folds ln2 into the coefficients (exp2 instead of exp, kills 12
// muls/path), and moves wave-uniform ab2[] to SGPRs via readfirstlane.

#define NSTEPS 365
#define NM     12
#define NK     21
#define PPW    8             // paths per wave
#define WAVES  4
#define BLOCK  (WAVES * 64)
#define PPB    (WAVES * PPW) // 32 paths per block

#define NCELL  (NM * NK)         // 252
#define WSZ    (2 * NCELL + NM)  // call@Kc, call@Kp, sumS -> 516

#define THETA_F (-0.1436f)
#define SIGMA_F (0.1213f)
#define THETA_D (-0.1436)
#define MU_D    (0.1686)
#define SIGMA_D (0.1213)
#define LOG2E_F (1.4426950408889634f)

template <int CTRL, int RMASK>
__device__ __forceinline__ float dpp_add(float v) {
    const int t = __builtin_amdgcn_update_dpp(0, __float_as_int(v), CTRL, RMASK, 0xf, true);
    return v + __int_as_float(t);
}
__device__ __forceinline__ float rdlane(float v, int l) {
    return __int_as_float(__builtin_amdgcn_readlane(__float_as_int(v), l));
}
__device__ __forceinline__ float rfl(float v) {
    return __int_as_float(__builtin_amdgcn_readfirstlane(__float_as_int(v)));
}

__global__ __launch_bounds__(BLOCK) void vg_paths_kernel(
    const float* __restrict__ S0p, const float* __restrict__ ratep,
    const int* __restrict__ indices, const float* __restrict__ z,
    const float* __restrict__ gam, const float* __restrict__ Kc,
    const float* __restrict__ Kp, float* __restrict__ acc, int MC)
{
    __shared__ float lacc[WSZ];
    const int tid = threadIdx.x;
    for (int i = tid; i < WSZ; i += BLOCK) lacc[i] = 0.f;
    __syncthreads();

    const int lane = tid & 63;
    const int wv   = tid >> 6;
    const int k    = lane % NK;          // strike col (lane 63 dummy)
    const int mg   = lane / NK;          // maturity group 0..2 (lane 63 -> 3)

    const float kc  = Kc[k];
    const float kp  = Kp[k];
    const float r_  = ratep[0];
    const float s0_ = S0p[0];
    const float w   = (float)((1.0 / MU_D) *
                      log(1.0 - THETA_D * MU_D - SIGMA_D * SIGMA_D * MU_D / 2.0));
    // log2-domain: S = exp2(ab2[m] + X2[m]) with incr scaled by log2(e)
    const float th2  = THETA_F * LOG2E_F;
    const float sg2  = SIGMA_F * LOG2E_F;
    const float rwh2 = (r_ + w) * LOG2E_F / (float)NSTEPS;
    const float l2s0 = log2f(s0_);

    float ab2[NM];                        // wave-uniform -> SGPRs
    #pragma unroll
    for (int m = 0; m < NM; ++m) ab2[m] = rfl(rwh2 * (float)indices[m] + l2s0);

    float ac_c[4], ac_p[4], sS[4];
    #pragma unroll
    for (int j = 0; j < 4; ++j) { ac_c[j] = 0.f; ac_p[j] = 0.f; sS[j] = 0.f; }

    const int o5 = min(lane + 320, 364);  // row-end clamp (dupes masked in scan)
    const bool m5 = (lane < 45);          // chunk-5 valid-lane mask

    auto loadp = [&](int p, float* zv, float* gv) {
        const int pc = min(p, MC - 1);
        const float* zp = z   + (size_t)pc * NSTEPS;
        const float* gp = gam + (size_t)pc * NSTEPS;
        #pragma unroll
        for (int c = 0; c < 5; ++c) {
            zv[c] = zp[lane + 64 * c];
            gv[c] = gp[lane + 64 * c];
        }
        zv[5] = zp[o5]; gv[5] = gp[o5];
    };

    // Two independent paths interleaved: fills DPP/readlane latency slots.
    auto process2 = [&](const float* zA, const float* gA, bool pvA,
                        const float* zB, const float* gB, bool pvB) {
        float XA[NM], XB[NM];
        float cA = 0.f, cB = 0.f;
        #pragma unroll
        for (int c = 0; c < 6; ++c) {
            const float ga = gA[c], gb = gB[c];
            float va = fmaf(th2, ga, sg2 * (sqrtf(ga) * zA[c]));
            float vb = fmaf(th2, gb, sg2 * (sqrtf(gb) * zB[c]));
            if (c == 5) { va = m5 ? va : 0.f; vb = m5 ? vb : 0.f; }
            va = dpp_add<0x111, 0xf>(va);  vb = dpp_add<0x111, 0xf>(vb);
            va = dpp_add<0x112, 0xf>(va);  vb = dpp_add<0x112, 0xf>(vb);
            va = dpp_add<0x114, 0xf>(va);  vb = dpp_add<0x114, 0xf>(vb);
            va = dpp_add<0x118, 0xf>(va);  vb = dpp_add<0x118, 0xf>(vb);
            va = dpp_add<0x142, 0xa>(va);  vb = dpp_add<0x142, 0xa>(vb);
            va = dpp_add<0x143, 0xc>(va);  vb = dpp_add<0x143, 0xc>(vb);
            XA[2 * c]     = cA + rdlane(va, 29 - 4 * c);
            XB[2 * c]     = cB + rdlane(vb, 29 - 4 * c);
            XA[2 * c + 1] = cA + rdlane(va, 59 - 4 * c);
            XB[2 * c + 1] = cB + rdlane(vb, 59 - 4 * c);
            cA += rdlane(va, 63);
            cB += rdlane(vb, 63);
        }
        #pragma unroll
        for (int half = 0; half < 2; ++half) {
            const float* X = half ? XB : XA;
            const bool  pv = half ? pvB : pvA;
            if (!pv) continue;                   // wave-uniform guard
            float S[NM];
            #pragma unroll
            for (int m = 0; m < NM; ++m) S[m] = exp2f(ab2[m] + X[m]);
            #pragma unroll
            for (int j = 0; j < 4; ++j) {
                const float Sj = (mg == 0) ? S[j] : (mg == 1) ? S[j + 4] : S[j + 8];
                ac_c[j] += fmaxf(Sj - kc, 0.f);
                ac_p[j] += fmaxf(Sj - kp, 0.f);
                sS[j]   += Sj;
            }
        }
    };

    // ---- fully-unrolled path loop, pair-wise double buffering ----
    const int p0 = blockIdx.x * PPB + wv * PPW;
    float zE[6], gE[6], zO[6], gO[6], zE2[6], gE2[6], zO2[6], gO2[6];
    loadp(p0 + 0, zE,  gE );  loadp(p0 + 1, zO,  gO );
    loadp(p0 + 2, zE2, gE2);  loadp(p0 + 3, zO2, gO2);
    process2(zE,  gE,  p0 + 0 < MC, zO,  gO,  p0 + 1 < MC);
    loadp(p0 + 4, zE,  gE );  loadp(p0 + 5, zO,  gO );
    process2(zE2, gE2, p0 + 2 < MC, zO2, gO2, p0 + 3 < MC);
    loadp(p0 + 6, zE2, gE2);  loadp(p0 + 7, zO2, gO2);
    process2(zE,  gE,  p0 + 4 < MC, zO,  gO,  p0 + 5 < MC);
    process2(zE2, gE2, p0 + 6 < MC, zO2, gO2, p0 + 7 < MC);

    // ---- block reduce: regs -> LDS -> global atomics ----
    if (lane < 63) {
        #pragma unroll
        for (int j = 0; j < 4; ++j) {
            const int cell = (4 * mg + j) * NK + k;
            atomicAdd(&lacc[cell],         ac_c[j]);
            atomicAdd(&lacc[NCELL + cell], ac_p[j]);
        }
        if (k == 0) {
            #pragma unroll
            for (int j = 0; j < 4; ++j)
                atomicAdd(&lacc[2 * NCELL + 4 * mg + j], sS[j]);
        }
    }
    __syncthreads();
    for (int i = tid; i < WSZ; i += BLOCK)
        atomicAdd(&acc[i], lacc[i]);
}

__global__ void vg_finalize_kernel(const float* __restrict__ acc,
                                   const float* __restrict__ ratep,
                                   const int* __restrict__ indices,
                                   const float* __restrict__ Kc,
                                   const float* __restrict__ Kp,
                                   float* __restrict__ out, int MC)
{
    const int i = blockIdx.x * blockDim.x + threadIdx.x;
    if (i >= 4 * NCELL) return;
    const int t    = i / NCELL;
    const int cell = i % NCELL;
    const int m    = cell / NK;
    const int kk   = cell % NK;
    const float r_   = ratep[0];
    const float im   = (float)indices[m];
    const float disc = expf(-r_ * im / (float)NSTEPS);
    const float cc = acc[cell];              // sum max(S-Kc,0)
    const float cp = acc[NCELL + cell];      // sum max(S-Kp,0)
    const float sS = acc[2 * NCELL + m];     // sum S
    const float fM = (float)MC;
    float v;
    if      (t == 0) v = cc;                          // call @ Kc
    else if (t == 1) v = cp - sS + fM * Kp[kk];       // put  @ Kp
    else if (t == 2) v = cp;                          // call @ Kp
    else             v = cc - sS + fM * Kc[kk];       // put  @ Kc
    out[i] = disc * v / fM;
}

extern "C" void kernel_launch(void* const* d_in, const int* in_sizes, int n_in,
                              void* d_out, int out_size, void* d_ws, size_t ws_size,
                              hipStream_t stream) {
    const float* S0      = (const float*)d_in[0];
    const float* rate    = (const float*)d_in[1];
    const int*   indices = (const int*)d_in[2];
    const float* z       = (const float*)d_in[3];
    const float* gamma_  = (const float*)d_in[4];
    const float* Kc      = (const float*)d_in[5];
    const float* Kp      = (const float*)d_in[6];

    const int MC = in_sizes[3] / NSTEPS;
    float* acc = (float*)d_ws;

    (void)hipMemsetAsync(d_ws, 0, WSZ * sizeof(float), stream);

    const int nb = (MC + PPB - 1) / PPB;
    vg_paths_kernel<<<nb, BLOCK, 0, stream>>>(S0, rate, indices, z, gamma_, Kc, Kp, acc, MC);

    vg_finalize_kernel<<<(4 * NCELL + 255) / 256, 256, 0, stream>>>(
        acc, rate, indices, Kc, Kp, (float*)d_out, MC);
}